// Round 8
// baseline (293.908 us; speedup 1.0000x reference)
//
#include <hip/hip_runtime.h>
#include <hip/hip_bf16.h>
#include <hip/hip_fp16.h>

#define N_NODES 50000
#define N_EDGES 800000
#define C_H 128
#define C_OUT 64
#define NBLK 196          // ceil(50000/256)
#define TSTRIDE 136       // LDS tile row stride in bf16
#define E_PAD 1200128     // >= 800000 + 8*50000 (per-bucket x2 padding), 1024-aligned
#define MM_BLKS 782       // ceil(50000/64) row-tiles for the XW1 matmul
#define TILE_N 6250       // src-tile width: 6250 rows x 256 B = 1.6 MB (L2-resident)
#define GB 782            // gather blocks: 64 nodes/block, co-resident single generation

typedef __attribute__((ext_vector_type(8))) short bf16x8;
typedef __attribute__((ext_vector_type(4))) float f32x4;

static __device__ __forceinline__ float bf_lo(unsigned int u) { return __uint_as_float(u << 16); }
static __device__ __forceinline__ float bf_hi(unsigned int u) { return __uint_as_float(u & 0xffff0000u); }
static __device__ __forceinline__ unsigned short f2bf(float f) {
    __hip_bfloat16 h = __float2bfloat16(f);
    return *(unsigned short*)&h;
}
static __device__ __forceinline__ unsigned int pack2(float a, float b) {
    return (unsigned int)f2bf(a) | ((unsigned int)f2bf(b) << 16);
}
static __device__ __forceinline__ unsigned short f2h_bits(float f) {
    union { __half h; unsigned short u; } c; c.h = __float2half_rn(f); return c.u;
}
static __device__ __forceinline__ float h_bits2f(unsigned short u) {
    union { __half h; unsigned short u; } c; c.u = u; return __half2float(c.h);
}

// ================= prep: (dst,src-tile) hist(+rank) + pack W + zero epay ==========
// block ranges: [0,3125) hist | [3125,3413) pack | [3413,4585) zero
__global__ void prep_kernel(const int* __restrict__ src, const int* __restrict__ dst,
                            int* __restrict__ counts2,
                            int* __restrict__ rank,
                            const float* __restrict__ W1, const float* __restrict__ W2,
                            const float* __restrict__ W3, const float* __restrict__ Wd1,
                            const float* __restrict__ Wd2,
                            unsigned short* __restrict__ P1, unsigned short* __restrict__ P2,
                            unsigned short* __restrict__ P3, unsigned short* __restrict__ Pd1,
                            unsigned short* __restrict__ Pd2,
                            unsigned int* __restrict__ epay) {
    int b = blockIdx.x;
    if (b < 3125) {                               // hist over (dst, src-tile), capture rank
        int e = b * 256 + threadIdx.x;
        int d = dst[e], s = src[e];
        int t = s / TILE_N;                       // 0..7
        rank[e] = atomicAdd(&counts2[d * 8 + t], 1);
    } else if (b < 3413) {                        // pack weights
        int idx = (b - 3125) * 256 + threadIdx.x;
        if (idx < 4 * 16384) {
            int which = idx >> 14;
            int r = idx & 16383;
            const float* W = (which == 0) ? W1 : (which == 1) ? W2 : (which == 2) ? W3 : Wd1;
            unsigned short* P = (which == 0) ? P1 : (which == 1) ? P2 : (which == 2) ? P3 : Pd1;
            int j = r & 7, lane = (r >> 3) & 63, t = r >> 9;
            int nb = t & 7, kb = t >> 3;          // NB=8
            int k = kb * 32 + ((lane >> 4) << 3) + j;
            int n = nb * 16 + (lane & 15);
            P[r] = f2bf(W[(size_t)k * 128 + n]);
        } else {
            int r = idx - 65536;
            if (r < 8192) {
                int j = r & 7, lane = (r >> 3) & 63, t = r >> 9;
                int nb = t & 3, kb = t >> 2;      // NB=4
                int k = kb * 32 + ((lane >> 4) << 3) + j;
                int n = nb * 16 + (lane & 15);
                Pd2[r] = f2bf(Wd2[(size_t)k * 64 + n]);
            }
        }
    } else {                                      // zero epay: 1172 blocks x 1024 uints
        int i = (b - 3413) * 256 + threadIdx.x;
        *(uint4*)(epay + (size_t)i * 4) = make_uint4(0, 0, 0, 0);
    }
}

// ================= CSR scans (each (dst,tile) bucket padded to multiple of 2) =====
// scan1: raw degree -> dinv; pad buckets to x2; in-place exclusive bucket scan in
// counts2; padded row total feeds the block-level prefix.
__global__ void __launch_bounds__(256) scan1_kernel(int* __restrict__ counts2,
                                                    int* __restrict__ eblk,
                                                    int* __restrict__ bsum,
                                                    float* __restrict__ dinv) {
    __shared__ int ws[4];
    int i = blockIdx.x * 256 + threadIdx.x;
    int vp = 0;
    if (i < N_NODES) {
        int* c = counts2 + (size_t)i * 8;
        uint4 a = *(uint4*)c;
        uint4 bq = *(uint4*)(c + 4);
        int raw = a.x + a.y + a.z + a.w + bq.x + bq.y + bq.z + bq.w;
        dinv[i] = rsqrtf((float)raw + 1.0f);
        int run = 0, tv;
        tv = ((int)a.x + 1) & ~1;  a.x  = run; run += tv;
        tv = ((int)a.y + 1) & ~1;  a.y  = run; run += tv;
        tv = ((int)a.z + 1) & ~1;  a.z  = run; run += tv;
        tv = ((int)a.w + 1) & ~1;  a.w  = run; run += tv;
        tv = ((int)bq.x + 1) & ~1; bq.x = run; run += tv;
        tv = ((int)bq.y + 1) & ~1; bq.y = run; run += tv;
        tv = ((int)bq.z + 1) & ~1; bq.z = run; run += tv;
        tv = ((int)bq.w + 1) & ~1; bq.w = run; run += tv;
        vp = run;
        *(uint4*)c = a;
        *(uint4*)(c + 4) = bq;
    }
    int lane = threadIdx.x & 63, w = threadIdx.x >> 6;
    int x = vp;
    #pragma unroll
    for (int off = 1; off < 64; off <<= 1) {
        int t = __shfl_up(x, off, 64);
        if (lane >= off) x += t;
    }
    if (lane == 63) ws[w] = x;
    __syncthreads();
    if (threadIdx.x == 0) {
        int run = 0;
        #pragma unroll
        for (int k = 0; k < 4; ++k) { int t = ws[k]; ws[k] = run; run += t; }
        bsum[blockIdx.x] = run;
    }
    __syncthreads();
    if (i < N_NODES) eblk[i] = x - vp + ws[w];
}

// merged scan2+scan3
__global__ void __launch_bounds__(256) scanB_kernel(const int* __restrict__ eblk,
                                                    const int* __restrict__ bsum,
                                                    int* __restrict__ rowptr) {
    __shared__ int ws[4];
    __shared__ int sbo;
    int i = threadIdx.x;
    int v = (i < NBLK) ? bsum[i] : 0;
    int lane = i & 63, w = i >> 6;
    int x = v;
    #pragma unroll
    for (int off = 1; off < 64; off <<= 1) {
        int t = __shfl_up(x, off, 64);
        if (lane >= off) x += t;
    }
    if (lane == 63) ws[w] = x;
    __syncthreads();
    if (i == 0) {
        int run = 0;
        #pragma unroll
        for (int k = 0; k < 4; ++k) { int t = ws[k]; ws[k] = run; run += t; }
    }
    __syncthreads();
    int excl = x - v + ws[w];
    if (i == (int)blockIdx.x) sbo = excl;
    if (blockIdx.x == 0 && i == NBLK - 1) rowptr[N_NODES] = excl + v;
    __syncthreads();
    int g = blockIdx.x * 256 + threadIdx.x;
    if (g < N_NODES) rowptr[g] = eblk[g] + sbo;
}

// ================= heterogeneous: XW1 matmul + csr fill (bucket-ordered) ==========
__global__ void __launch_bounds__(256) fill_mm_kernel(
        const float* __restrict__ x, const unsigned short* __restrict__ P1,
        unsigned short* __restrict__ XW1,
        const int* __restrict__ src, const int* __restrict__ dst,
        const float* __restrict__ dinv,
        const int* __restrict__ rowptr, const int* __restrict__ counts2,
        const int* __restrict__ rank,
        unsigned int* __restrict__ epay) {
    int b = blockIdx.x;
    if (b < MM_BLKS) {
        const int lane = threadIdx.x & 63;
        const int wave = threadIdx.x >> 6;
        const int wid  = b * 4 + wave;
        if (wid * 16 >= N_NODES) return;          // exact: 3125 waves used
        const int node = wid * 16 + (lane & 15);
        const int quad = lane >> 4;
        f32x4 acc[8];
        #pragma unroll
        for (int nb = 0; nb < 8; ++nb) acc[nb] = (f32x4){0.f, 0.f, 0.f, 0.f};
        #pragma unroll
        for (int kb = 0; kb < 4; ++kb) {
            const float* p = x + (size_t)node * 128 + kb * 32 + quad * 8;
            float4 lo = *(const float4*)p;
            float4 hi = *(const float4*)(p + 4);
            union { bf16x8 v; unsigned int u[4]; } tmp;
            tmp.u[0] = pack2(lo.x, lo.y); tmp.u[1] = pack2(lo.z, lo.w);
            tmp.u[2] = pack2(hi.x, hi.y); tmp.u[3] = pack2(hi.z, hi.w);
            #pragma unroll
            for (int nb = 0; nb < 8; ++nb) {
                bf16x8 wf = *(const bf16x8*)(P1 + ((size_t)(kb * 8 + nb) * 64 + lane) * 8);
                acc[nb] = __builtin_amdgcn_mfma_f32_16x16x32_bf16(wf, tmp.v, acc[nb], 0, 0, 0);
            }
        }
        #pragma unroll
        for (int nb = 0; nb < 8; ++nb) {
            int ch = nb * 16 + quad * 4;
            uint2 o;
            o.x = pack2(acc[nb][0], acc[nb][1]);
            o.y = pack2(acc[nb][2], acc[nb][3]);
            *(uint2*)(XW1 + (size_t)node * C_H + ch) = o;
        }
    } else {
        int e = (b - MM_BLKS) * 256 + threadIdx.x;
        if (e < N_EDGES) {
            int d = dst[e], s = src[e];
            int t = s / TILE_N;
            int pos = rowptr[d] + counts2[d * 8 + t] + rank[e];
            float nrm = dinv[s] * dinv[d];
            epay[pos] = (unsigned int)s | ((unsigned int)f2h_bits(nrm) << 16);
        }
    }
}

// ============ 32-channel per-thread aggregation, per-tile lockstep walk ============
static __device__ __forceinline__ void fma8v(float* a, uint4 q, float nm) {
    a[0] = fmaf(bf_lo(q.x), nm, a[0]); a[1] = fmaf(bf_hi(q.x), nm, a[1]);
    a[2] = fmaf(bf_lo(q.y), nm, a[2]); a[3] = fmaf(bf_hi(q.y), nm, a[3]);
    a[4] = fmaf(bf_lo(q.z), nm, a[4]); a[5] = fmaf(bf_hi(q.z), nm, a[5]);
    a[6] = fmaf(bf_lo(q.w), nm, a[6]); a[7] = fmaf(bf_hi(q.w), nm, a[7]);
}

static __device__ __forceinline__ void agg32(
        const int* __restrict__ rowptr, const int* __restrict__ counts2,
        const unsigned int* __restrict__ epay,
        const unsigned short* __restrict__ hin,
        const float* __restrict__ dinv,
        int node, int cb, float* acc) {
    const unsigned short* hc = hin + cb;
    float di = dinv[node], dii = di * di;
    {   // self term
        const unsigned short* rp = hc + (size_t)node * C_H;
        uint4 q0 = *(const uint4*)rp,        q1 = *(const uint4*)(rp + 8);
        uint4 q2 = *(const uint4*)(rp + 16), q3 = *(const uint4*)(rp + 24);
        fma8v(acc + 0, q0, dii); fma8v(acc + 8, q1, dii);
        fma8v(acc + 16, q2, dii); fma8v(acc + 24, q3, dii);
    }
    int base = rowptr[node];
    int rend = rowptr[node + 1];
    const int* boff = counts2 + (size_t)node * 8;
    // lockstep over src-tiles: all lanes advance tiles together -> L2-resident tile
    #pragma unroll 1
    for (int t = 0; t < 8; ++t) {
        int b0 = base + boff[t];
        int b1 = (t == 7) ? rend : base + boff[t + 1];
        for (int p = b0; p < b1; p += 2) {
            uint2 ev = *(const uint2*)(epay + p);
            const unsigned short* ra = hc + (size_t)(ev.x & 0xffffu) * C_H;
            const unsigned short* rb = hc + (size_t)(ev.y & 0xffffu) * C_H;
            uint4 a0 = *(const uint4*)ra,        a1 = *(const uint4*)(ra + 8);
            uint4 a2 = *(const uint4*)(ra + 16), a3 = *(const uint4*)(ra + 24);
            uint4 c0 = *(const uint4*)rb,        c1 = *(const uint4*)(rb + 8);
            uint4 c2 = *(const uint4*)(rb + 16), c3 = *(const uint4*)(rb + 24);
            float na = h_bits2f((unsigned short)(ev.x >> 16));
            float nb = h_bits2f((unsigned short)(ev.y >> 16));
            fma8v(acc + 0, a0, na); fma8v(acc + 8, a1, na);
            fma8v(acc + 16, a2, na); fma8v(acc + 24, a3, na);
            fma8v(acc + 0, c0, nb); fma8v(acc + 8, c1, nb);
            fma8v(acc + 16, c2, nb); fma8v(acc + 24, c3, nb);
        }
    }
}

// ================= layer 1: pure gather(XW1) + bias + relu -> bf16 =================
// 64 nodes/block x 4 thr/node x 32 ch; grid GB=782 -> single co-resident generation.
__global__ void __launch_bounds__(256, 4) gather1_kernel(
        const int* __restrict__ rowptr, const int* __restrict__ counts2,
        const unsigned int* __restrict__ epay,
        const float* __restrict__ dinv,
        const unsigned short* __restrict__ hin,
        const float* __restrict__ bias,
        unsigned short* __restrict__ out) {
    const int t = threadIdx.x;
    const int node = blockIdx.x * 64 + (t >> 2);
    if (node >= N_NODES) return;
    const int cb = (t & 3) << 5;

    float acc[32];
    #pragma unroll
    for (int j = 0; j < 32; ++j) acc[j] = 0.f;
    agg32(rowptr, counts2, epay, hin, dinv, node, cb, acc);

    #pragma unroll
    for (int g = 0; g < 4; ++g) {
        float4 ba = *(const float4*)(bias + cb + g * 8);
        float4 bb = *(const float4*)(bias + cb + g * 8 + 4);
        float v0 = fmaxf(acc[g*8+0] + ba.x, 0.f), v1 = fmaxf(acc[g*8+1] + ba.y, 0.f);
        float v2 = fmaxf(acc[g*8+2] + ba.z, 0.f), v3 = fmaxf(acc[g*8+3] + ba.w, 0.f);
        float v4 = fmaxf(acc[g*8+4] + bb.x, 0.f), v5 = fmaxf(acc[g*8+5] + bb.y, 0.f);
        float v6 = fmaxf(acc[g*8+6] + bb.z, 0.f), v7 = fmaxf(acc[g*8+7] + bb.w, 0.f);
        uint4 o;
        o.x = pack2(v0, v1); o.y = pack2(v2, v3);
        o.z = pack2(v4, v5); o.w = pack2(v6, v7);
        *(uint4*)(out + (size_t)node * C_H + cb + g * 8) = o;
    }
}

// ========== fused layer: co-resident gather (64 nodes) -> LDS -> MFMA chain ========
template <bool FINAL>
__global__ void __launch_bounds__(256, 4) fused_layer_kernel(
        const int* __restrict__ rowptr, const int* __restrict__ counts2,
        const unsigned int* __restrict__ epay,
        const float* __restrict__ dinv,
        const unsigned short* __restrict__ hin,
        const unsigned short* __restrict__ Wp,
        const float* __restrict__ bias,
        const unsigned short* __restrict__ Wd1p,
        const float* __restrict__ bd1,
        const unsigned short* __restrict__ Wd2p,
        const float* __restrict__ bd2,
        unsigned short* __restrict__ out_b,
        float* __restrict__ out_f) {
    __shared__ unsigned short sA[64 * TSTRIDE];
    __shared__ unsigned short sB[64 * TSTRIDE];
    const int t = threadIdx.x;

    // ---- phase A: lockstep gather of 64 agg rows into sA ----
    {
        const int ln = t >> 2;
        const int node = blockIdx.x * 64 + ln;
        const int cb = (t & 3) << 5;
        float acc[32];
        #pragma unroll
        for (int j = 0; j < 32; ++j) acc[j] = 0.f;
        if (node < N_NODES)
            agg32(rowptr, counts2, epay, hin, dinv, node, cb, acc);
        #pragma unroll
        for (int g = 0; g < 4; ++g) {
            uint4 o;
            o.x = pack2(acc[g*8+0], acc[g*8+1]); o.y = pack2(acc[g*8+2], acc[g*8+3]);
            o.z = pack2(acc[g*8+4], acc[g*8+5]); o.w = pack2(acc[g*8+6], acc[g*8+7]);
            *(uint4*)(sA + ln * TSTRIDE + cb + g * 8) = o;
        }
    }
    __syncthreads();

    const int lane = t & 63, wave = t >> 6, quad = lane >> 4, row = lane & 15;
    const int nb0 = 2 * wave, nb1 = 2 * wave + 1;

    // ---- mm1: relu(sA @ Wp + bias) ; 4 row-tiles per block ----
    #pragma unroll 1
    for (int rt = 0; rt < 4; ++rt) {
        const int lrow = rt * 16 + row;
        const int node = blockIdx.x * 64 + lrow;
        f32x4 acc0 = (f32x4){0.f, 0.f, 0.f, 0.f};
        f32x4 acc1 = (f32x4){0.f, 0.f, 0.f, 0.f};
        #pragma unroll
        for (int kb = 0; kb < 4; ++kb) {
            bf16x8 hf = *(const bf16x8*)(sA + lrow * TSTRIDE + kb * 32 + quad * 8);
            bf16x8 wf0 = *(const bf16x8*)(Wp + ((size_t)(kb * 8 + nb0) * 64 + lane) * 8);
            bf16x8 wf1 = *(const bf16x8*)(Wp + ((size_t)(kb * 8 + nb1) * 64 + lane) * 8);
            acc0 = __builtin_amdgcn_mfma_f32_16x16x32_bf16(wf0, hf, acc0, 0, 0, 0);
            acc1 = __builtin_amdgcn_mfma_f32_16x16x32_bf16(wf1, hf, acc1, 0, 0, 0);
        }
        float4 ba0 = *(const float4*)(bias + nb0 * 16 + quad * 4);
        float4 ba1 = *(const float4*)(bias + nb1 * 16 + quad * 4);
        float v00 = fmaxf(acc0[0] + ba0.x, 0.f), v01 = fmaxf(acc0[1] + ba0.y, 0.f);
        float v02 = fmaxf(acc0[2] + ba0.z, 0.f), v03 = fmaxf(acc0[3] + ba0.w, 0.f);
        float v10 = fmaxf(acc1[0] + ba1.x, 0.f), v11 = fmaxf(acc1[1] + ba1.y, 0.f);
        float v12 = fmaxf(acc1[2] + ba1.z, 0.f), v13 = fmaxf(acc1[3] + ba1.w, 0.f);
        uint2 o0, o1;
        o0.x = pack2(v00, v01); o0.y = pack2(v02, v03);
        o1.x = pack2(v10, v11); o1.y = pack2(v12, v13);
        if (!FINAL) {
            if (node < N_NODES) {
                *(uint2*)(out_b + (size_t)node * C_H + nb0 * 16 + quad * 4) = o0;
                *(uint2*)(out_b + (size_t)node * C_H + nb1 * 16 + quad * 4) = o1;
            }
        } else {
            *(uint2*)(sB + lrow * TSTRIDE + nb0 * 16 + quad * 4) = o0;
            *(uint2*)(sB + lrow * TSTRIDE + nb1 * 16 + quad * 4) = o1;
        }
    }
    if (!FINAL) return;

    __syncthreads();
    // ---- mm2: relu(sB @ Wd1 + bd1) -> sA ----
    #pragma unroll 1
    for (int rt = 0; rt < 4; ++rt) {
        const int lrow = rt * 16 + row;
        f32x4 acc0 = (f32x4){0.f, 0.f, 0.f, 0.f};
        f32x4 acc1 = (f32x4){0.f, 0.f, 0.f, 0.f};
        #pragma unroll
        for (int kb = 0; kb < 4; ++kb) {
            bf16x8 hf = *(const bf16x8*)(sB + lrow * TSTRIDE + kb * 32 + quad * 8);
            bf16x8 wf0 = *(const bf16x8*)(Wd1p + ((size_t)(kb * 8 + nb0) * 64 + lane) * 8);
            bf16x8 wf1 = *(const bf16x8*)(Wd1p + ((size_t)(kb * 8 + nb1) * 64 + lane) * 8);
            acc0 = __builtin_amdgcn_mfma_f32_16x16x32_bf16(wf0, hf, acc0, 0, 0, 0);
            acc1 = __builtin_amdgcn_mfma_f32_16x16x32_bf16(wf1, hf, acc1, 0, 0, 0);
        }
        float4 ba0 = *(const float4*)(bd1 + nb0 * 16 + quad * 4);
        float4 ba1 = *(const float4*)(bd1 + nb1 * 16 + quad * 4);
        float v00 = fmaxf(acc0[0] + ba0.x, 0.f), v01 = fmaxf(acc0[1] + ba0.y, 0.f);
        float v02 = fmaxf(acc0[2] + ba0.z, 0.f), v03 = fmaxf(acc0[3] + ba0.w, 0.f);
        float v10 = fmaxf(acc1[0] + ba1.x, 0.f), v11 = fmaxf(acc1[1] + ba1.y, 0.f);
        float v12 = fmaxf(acc1[2] + ba1.z, 0.f), v13 = fmaxf(acc1[3] + ba1.w, 0.f);
        uint2 o0, o1;
        o0.x = pack2(v00, v01); o0.y = pack2(v02, v03);
        o1.x = pack2(v10, v11); o1.y = pack2(v12, v13);
        *(uint2*)(sA + lrow * TSTRIDE + nb0 * 16 + quad * 4) = o0;
        *(uint2*)(sA + lrow * TSTRIDE + nb1 * 16 + quad * 4) = o1;
    }
    __syncthreads();

    // ---- mm3: sA @ Wd2 + bd2 -> sigmoid -> out_f ----
    #pragma unroll 1
    for (int rt = 0; rt < 4; ++rt) {
        const int lrow = rt * 16 + row;
        const int node = blockIdx.x * 64 + lrow;
        f32x4 acc = (f32x4){0.f, 0.f, 0.f, 0.f};
        #pragma unroll
        for (int kb = 0; kb < 4; ++kb) {
            bf16x8 hf = *(const bf16x8*)(sA + lrow * TSTRIDE + kb * 32 + quad * 8);
            bf16x8 wf = *(const bf16x8*)(Wd2p + ((size_t)(kb * 4 + wave) * 64 + lane) * 8);
            acc = __builtin_amdgcn_mfma_f32_16x16x32_bf16(wf, hf, acc, 0, 0, 0);
        }
        if (node < N_NODES) {
            int ch = wave * 16 + quad * 4;
            float4 b4 = *(const float4*)(bd2 + ch);
            float4 rr;
            rr.x = 1.f / (1.f + expf(-(acc[0] + b4.x)));
            rr.y = 1.f / (1.f + expf(-(acc[1] + b4.y)));
            rr.z = 1.f / (1.f + expf(-(acc[2] + b4.z)));
            rr.w = 1.f / (1.f + expf(-(acc[3] + b4.w)));
            *(float4*)(out_f + (size_t)node * C_OUT + ch) = rr;
        }
    }
}

extern "C" void kernel_launch(void* const* d_in, const int* in_sizes, int n_in,
                              void* d_out, int out_size, void* d_ws, size_t ws_size,
                              hipStream_t stream) {
    const float* x   = (const float*)d_in[0];
    const int*   ei  = (const int*)d_in[1];
    const float* W1  = (const float*)d_in[2];
    const float* b1  = (const float*)d_in[3];
    const float* W2  = (const float*)d_in[4];
    const float* b2  = (const float*)d_in[5];
    const float* W3  = (const float*)d_in[6];
    const float* b3  = (const float*)d_in[7];
    const float* Wd1 = (const float*)d_in[8];
    const float* bd1 = (const float*)d_in[9];
    const float* Wd2 = (const float*)d_in[10];
    const float* bd2 = (const float*)d_in[11];

    const int* src = ei;
    const int* dst = ei + N_EDGES;

    char* base = (char*)d_ws;
    size_t off = 0;
    auto alloc = [&](size_t bytes) { char* p = base + off; off += (bytes + 255) & ~size_t(255); return p; };
    int*            counts2 = (int*)alloc((size_t)N_NODES * 8 * 4);   // (dst,tile) hist -> padded bucket offsets
    unsigned int*   epay   = (unsigned int*)alloc((size_t)E_PAD * 4);
    int*            rank   = (int*)alloc((size_t)N_EDGES * 4);
    float*          dinv   = (float*)alloc(N_NODES * 4);
    int*            rowptr = (int*)alloc((N_NODES + 1) * 4);
    int*            eblk   = (int*)alloc(N_NODES * 4);
    int*            bsum   = (int*)alloc(256 * 4);
    unsigned short* XW1    = (unsigned short*)alloc((size_t)N_NODES * C_H * 2);
    unsigned short* bufA   = (unsigned short*)alloc((size_t)N_NODES * C_H * 2);
    unsigned short* bufB   = (unsigned short*)alloc((size_t)N_NODES * C_H * 2);
    unsigned short* P1     = (unsigned short*)alloc(128 * 128 * 2);
    unsigned short* P2     = (unsigned short*)alloc(128 * 128 * 2);
    unsigned short* P3     = (unsigned short*)alloc(128 * 128 * 2);
    unsigned short* Pd1    = (unsigned short*)alloc(128 * 128 * 2);
    unsigned short* Pd2    = (unsigned short*)alloc(128 * 64 * 2);

    const int T = 256;
    dim3 blk(T);
    dim3 gN((N_NODES + T - 1) / T);            // 196
    dim3 gPrep(3125 + 288 + 1172);             // hist + pack + zero (E_PAD/1024)
    dim3 gFillMM(MM_BLKS + 3125);              // mm + fill
    dim3 gGB(GB);                              // 782 co-resident gather blocks

    hipMemsetAsync(counts2, 0, (size_t)N_NODES * 8 * 4, stream);
    prep_kernel<<<gPrep, blk, 0, stream>>>(src, dst, counts2, rank,
                                           W1, W2, W3, Wd1, Wd2,
                                           P1, P2, P3, Pd1, Pd2, epay);
    scan1_kernel<<<gN, blk, 0, stream>>>(counts2, eblk, bsum, dinv);
    scanB_kernel<<<gN, blk, 0, stream>>>(eblk, bsum, rowptr);
    fill_mm_kernel<<<gFillMM, blk, 0, stream>>>(x, P1, XW1, src, dst, dinv,
                                                rowptr, counts2, rank, epay);

    // ---- layer 1: relu(agg(XW1) + b1) -> bufA ----
    gather1_kernel<<<gGB, blk, 0, stream>>>(rowptr, counts2, epay, dinv, XW1, b1, bufA);
    // ---- layer 2 ----
    fused_layer_kernel<false><<<gGB, blk, 0, stream>>>(
        rowptr, counts2, epay, dinv, bufA, P2, b2, nullptr, nullptr, nullptr, nullptr, bufB, nullptr);
    // ---- layer 3 + dense head ----
    fused_layer_kernel<true><<<gGB, blk, 0, stream>>>(
        rowptr, counts2, epay, dinv, bufB, P3, b3, Pd1, bd1, Pd2, bd2, nullptr, (float*)d_out);
}